// Round 7
// baseline (5337.773 us; speedup 1.0000x reference)
//
#include <hip/hip_runtime.h>
#include <math.h>

// ---------------------------------------------------------------------------
// Sender: LSTM + Gumbel straight-through decode, 32 steps.
// Round 7: XCD-aware block swizzle. Grids transposed to dim3(B/128, V/64) so
// dispatch-linear index % 8 == batch row-block. Under round-robin XCD
// assignment each XCD pins ONE 655KB A row-block in its 4MB L2 (64 strip
// re-reads become L2 hits) and streams weights once from LLC. Identical
// arithmetic to round 6 (pure scheduling change).
//   GEMMs: 128 thr / 2 waves, tile 128(M)x64(N), wave tile 64x64, BK=32,
//   24KB LDS, 512 blocks = 2 blocks/CU. f16 2-way split (3 MFMA/product).
//   Fused epilogues: gates->LSTM cell; logits->sampling partials.
// ---------------------------------------------------------------------------

typedef _Float16 f16;
typedef f16 f16x8 __attribute__((ext_vector_type(8)));
typedef float f32x4 __attribute__((ext_vector_type(4)));

#define F16_MIN_NORM 6.104e-5f

__device__ __forceinline__ void split_f16(float v, f16& h, f16& l) {
  f16 h0 = (fabsf(v) < F16_MIN_NORM) ? (f16)0.0f : (f16)v;
  float r = (v - (float)h0) * 4096.0f;
  h = h0; l = (f16)r;
}

__device__ __forceinline__ float sigm(float x) { return 1.0f / (1.0f + expf(-x)); }

#define GLOAD_LDS16(gsrc, ldst)                                               \
  __builtin_amdgcn_global_load_lds(                                           \
      (const __attribute__((address_space(1))) unsigned int*)(const void*)(gsrc), \
      (__attribute__((address_space(3))) unsigned int*)(void*)(ldst), 16, 0, 0)

// --------------------------- threefry / gumbel -----------------------------

__device__ __forceinline__ unsigned tf_rotl(unsigned x, int r) {
  return (x << r) | (x >> (32 - r));
}

// JAX threefry2x32-20, key (0,42), partitionable: draw = x0_out ^ x1_out.
__device__ inline float gumbel_at(unsigned idx) {
  const unsigned ks0 = 0u;
  const unsigned ks1 = 42u;
  const unsigned ks2 = 0x1BD11BDAu ^ ks0 ^ ks1;
  unsigned x0 = 0u + ks0;
  unsigned x1 = idx + ks1;
#define TFR(rot) { x0 += x1; x1 = tf_rotl(x1, rot); x1 ^= x0; }
  TFR(13) TFR(15) TFR(26) TFR(6)
  x0 += ks1; x1 += ks2 + 1u;
  TFR(17) TFR(29) TFR(16) TFR(24)
  x0 += ks2; x1 += ks0 + 2u;
  TFR(13) TFR(15) TFR(26) TFR(6)
  x0 += ks0; x1 += ks1 + 3u;
  TFR(17) TFR(29) TFR(16) TFR(24)
  x0 += ks1; x1 += ks2 + 4u;
  TFR(13) TFR(15) TFR(26) TFR(6)
  x0 += ks2; x1 += ks0 + 5u;
#undef TFR
  const unsigned bits = x0 ^ x1;
  const float f = __uint_as_float((bits >> 9) | 0x3F800000u) - 1.0f;
  const float tiny = 1.17549435082228751e-38f;
  const float u = fmaxf(tiny, f * (1.0f - tiny) + tiny);
  return -logf(-logf(u));
}

// ------------------------- setup / pack kernels ----------------------------

__global__ void init_kernel(float* __restrict__ out, const float* __restrict__ emb,
                            f16* __restrict__ e0, f16* __restrict__ e1,
                            const int* __restrict__ startp, int Tp1, int V, int E) {
  const int b = blockIdx.x;
  const int start = *startp;
  float* orow = out + (size_t)b * Tp1 * V;
  const int tq = start >> 2;
  for (int v4 = threadIdx.x; v4 < V / 4; v4 += blockDim.x) {
    float4 v = make_float4(0.f, 0.f, 0.f, 0.f);
    if (v4 == tq) ((float*)&v)[start & 3] = 1.0f;
    ((float4*)orow)[v4] = v;
  }
  if (threadIdx.x < E) {
    const float v = emb[(size_t)start * E + threadIdx.x];
    f16 h, l; split_f16(v, h, l);
    e0[(size_t)b * E + threadIdx.x] = h;
    e1[(size_t)b * E + threadIdx.x] = l;
  }
}

// packed gate col p: gate q=(p>>4)&3, unit u=((p>>6)<<4)+(p&15); orig row
// n' = q*H + u. wpk[p][k] = k<E ? wih[n'][k] : whh[n'][k-E], split.
__global__ void pack_gates_kernel(const float* __restrict__ wih,
                                  const float* __restrict__ whh,
                                  f16* __restrict__ w0, f16* __restrict__ w1,
                                  int E, int H, int K) {
  const int k = blockIdx.x * blockDim.x + threadIdx.x;
  const int p = blockIdx.y;
  if (k >= K) return;
  const int n = ((p >> 4) & 3) * H + ((p >> 6) << 4) + (p & 15);
  const float v = (k < E) ? wih[(size_t)n * E + k] : whh[(size_t)n * H + (k - E)];
  f16 h, l; split_f16(v, h, l);
  w0[(size_t)p * K + k] = h;
  w1[(size_t)p * K + k] = l;
}

__global__ void pack_bias_kernel(const float* __restrict__ bih,
                                 const float* __restrict__ bhh,
                                 float* __restrict__ bi, float* __restrict__ bh, int H) {
  const int p = blockIdx.x * blockDim.x + threadIdx.x;
  const int n = ((p >> 4) & 3) * H + ((p >> 6) << 4) + (p & 15);
  bi[p] = bih[n];
  bh[p] = bhh[n];
}

__global__ void split_kernel(const float* __restrict__ in,
                             f16* __restrict__ o0, f16* __restrict__ o1, int n) {
  const int i = blockIdx.x * blockDim.x + threadIdx.x;
  if (i < n) { f16 h, l; split_f16(in[i], h, l); o0[i] = h; o1[i] = l; }
}

// ----------------------- shared K-loop building block ----------------------
// block 128 thr / 2 waves, tile 128x64, BK=32. wave0 stages hi planes,
// wave1 stages lo planes. lane->LDS: row lane>>2, col (lane&3)*8 (16B/lane).
// SWIZZLE: blockIdx.x = batch row-block (fast dim -> XCD), blockIdx.y = strip.

#define MFMA_DECLS                                                            \
  const int tid  = threadIdx.x;                                               \
  const int lane = tid & 63;                                                  \
  const int wid  = tid >> 6;                                                  \
  const int bm   = blockIdx.x * 128;                                          \
  const int bn   = blockIdx.y * 64;                                           \
  const int wm   = wid * 64;                                                  \
  const int fr   = lane & 15;                                                 \
  const int fk   = (lane >> 4) * 8;                                           \
  const int srow = lane >> 2;                                                 \
  const int scol = (lane & 3) * 8;                                            \
  f32x4 acc0[4][4], acc1[4][4];                                               \
  _Pragma("unroll") for (int i = 0; i < 4; ++i)                               \
  _Pragma("unroll") for (int j = 0; j < 4; ++j) {                             \
    acc0[i][j] = (f32x4)0.0f; acc1[i][j] = (f32x4)0.0f; }

#define MFMA_STAGE(a0s, a1s, lda, ka, b0s, b1s, ldb, kb)                      \
  __syncthreads();                                                            \
  if (wid == 0) {                                                             \
    _Pragma("unroll") for (int s = 0; s < 8; ++s)                             \
      GLOAD_LDS16((a0s) + (size_t)(bm + s * 16 + srow) * (lda) + (ka) + scol, \
                  &ldsA0[s * 16][0]);                                         \
    _Pragma("unroll") for (int s = 0; s < 4; ++s)                             \
      GLOAD_LDS16((b0s) + (size_t)(bn + s * 16 + srow) * (ldb) + (kb) + scol, \
                  &ldsB0[s * 16][0]);                                         \
  } else {                                                                    \
    _Pragma("unroll") for (int s = 0; s < 8; ++s)                             \
      GLOAD_LDS16((a1s) + (size_t)(bm + s * 16 + srow) * (lda) + (ka) + scol, \
                  &ldsA1[s * 16][0]);                                         \
    _Pragma("unroll") for (int s = 0; s < 4; ++s)                             \
      GLOAD_LDS16((b1s) + (size_t)(bn + s * 16 + srow) * (ldb) + (kb) + scol, \
                  &ldsB1[s * 16][0]);                                         \
  }                                                                           \
  __syncthreads();

#define MFMA_COMPUTE                                                          \
  {                                                                           \
    f16x8 a0[4], a1[4], b0[4], b1[4];                                         \
    _Pragma("unroll") for (int i = 0; i < 4; ++i) {                           \
      a0[i] = *(const f16x8*)&ldsA0[wm + i * 16 + fr][fk];                    \
      a1[i] = *(const f16x8*)&ldsA1[wm + i * 16 + fr][fk];                    \
      b0[i] = *(const f16x8*)&ldsB0[i * 16 + fr][fk];                         \
      b1[i] = *(const f16x8*)&ldsB1[i * 16 + fr][fk];                         \
    }                                                                         \
    _Pragma("unroll") for (int i = 0; i < 4; ++i)                             \
    _Pragma("unroll") for (int j = 0; j < 4; ++j) {                           \
      acc0[i][j] = __builtin_amdgcn_mfma_f32_16x16x32_f16(a0[i], b0[j], acc0[i][j], 0, 0, 0); \
      acc1[i][j] = __builtin_amdgcn_mfma_f32_16x16x32_f16(a0[i], b1[j], acc1[i][j], 0, 0, 0); \
      acc1[i][j] = __builtin_amdgcn_mfma_f32_16x16x32_f16(a1[i], b0[j], acc1[i][j], 0, 0, 0); \
    }                                                                         \
  }

// ------------------- h0 GEMM: h0 = t @ aff_w^T + aff_b ---------------------
__global__ __launch_bounds__(128, 1) void h0_kernel(
    const f16* __restrict__ t0, const f16* __restrict__ t1, int F,
    const f16* __restrict__ aw0, const f16* __restrict__ aw1,
    const float* __restrict__ affb,
    f16* __restrict__ h0p, f16* __restrict__ h1p, int H,
    float* __restrict__ czero)
{
  __shared__ f16 ldsA0[128][32], ldsA1[128][32], ldsB0[64][32], ldsB1[64][32];
  MFMA_DECLS
  for (int kk = 0; kk < F; kk += 32) {
    MFMA_STAGE(t0, t1, F, kk, aw0, aw1, F, kk)
    MFMA_COMPUTE
  }
  const int q4 = (lane >> 4) * 4;
  const float s12 = 1.0f / 4096.0f;
#pragma unroll
  for (int j = 0; j < 4; ++j) {
    const int col = bn + j * 16 + fr;
    const float bb = affb[col];
#pragma unroll
    for (int i = 0; i < 4; ++i) {
#pragma unroll
      for (int r = 0; r < 4; ++r) {
        const int row = bm + wm + i * 16 + q4 + r;
        const float v = (acc0[i][j][r] + acc1[i][j][r] * s12) + bb;
        f16 hh, hl; split_f16(v, hh, hl);
        const size_t off = (size_t)row * H + col;
        h0p[off] = hh; h1p[off] = hl;
        czero[off] = 0.0f;
      }
    }
  }
}

// ---------------- gates GEMM + fused LSTM cell epilogue --------------------
__global__ __launch_bounds__(128, 1) void gates_kernel(
    const f16* __restrict__ e0, const f16* __restrict__ e1, int E,
    const f16* __restrict__ hin0, const f16* __restrict__ hin1, int H,
    const f16* __restrict__ w0, const f16* __restrict__ w1, int K,
    const float* __restrict__ bi, const float* __restrict__ bh,
    float* __restrict__ cbuf,
    f16* __restrict__ hout0, f16* __restrict__ hout1)
{
  __shared__ f16 ldsA0[128][32], ldsA1[128][32], ldsB0[64][32], ldsB1[64][32];
  MFMA_DECLS
  for (int kk = 0; kk < K; kk += 32) {
    const f16* a0s; const f16* a1s; int lda, ka;
    if (kk < E) { a0s = e0;   a1s = e1;   lda = E; ka = kk; }
    else        { a0s = hin0; a1s = hin1; lda = H; ka = kk - E; }
    MFMA_STAGE(a0s, a1s, lda, ka, w0, w1, K, kk)
    MFMA_COMPUTE
  }
  // epilogue: packed cols -> unit u = (bn>>2)+fr, gate q = j.
  const int q4 = (lane >> 4) * 4;
  const float s12 = 1.0f / 4096.0f;
  float biv[4], bhv[4];
#pragma unroll
  for (int j = 0; j < 4; ++j) {
    const int col = bn + j * 16 + fr;
    biv[j] = bi[col]; bhv[j] = bh[col];
  }
  const int nunit = (bn >> 2) + fr;
#pragma unroll
  for (int i = 0; i < 4; ++i) {
#pragma unroll
    for (int r = 0; r < 4; ++r) {
      const int row = bm + wm + i * 16 + q4 + r;
      float gv[4];
#pragma unroll
      for (int j = 0; j < 4; ++j)
        gv[j] = ((acc0[i][j][r] + acc1[i][j][r] * s12) + biv[j]) + bhv[j];
      const size_t off = (size_t)row * H + nunit;
      const float c = cbuf[off];
      const float cn = __fadd_rn(__fmul_rn(sigm(gv[1]), c),
                                 __fmul_rn(sigm(gv[0]), tanhf(gv[2])));
      const float hn = __fmul_rn(sigm(gv[3]), tanhf(cn));
      cbuf[off] = cn;
      f16 hh, hl; split_f16(hn, hh, hl);
      hout0[off] = hh; hout1[off] = hl;
    }
  }
}

// ------------- logits GEMM + fused sampling partials epilogue --------------
__global__ __launch_bounds__(128, 1) void logits_kernel(
    const f16* __restrict__ h0p, const f16* __restrict__ h1p, int H,
    const f16* __restrict__ w0, const f16* __restrict__ w1,
    const float* __restrict__ lpb,
    float* __restrict__ partM, float* __restrict__ partS, int* __restrict__ partI,
    int step, int B, int V)
{
  __shared__ f16 ldsA0[128][32], ldsA1[128][32], ldsB0[64][32], ldsB1[64][32];
  MFMA_DECLS
  for (int kk = 0; kk < H; kk += 32) {
    MFMA_STAGE(h0p, h1p, H, kk, w0, w1, H, kk)
    MFMA_COMPUTE
  }
  const int q4 = (lane >> 4) * 4;
  const float s12 = 1.0f / 4096.0f;
  float bv[4];
#pragma unroll
  for (int j = 0; j < 4; ++j) bv[j] = lpb[bn + j * 16 + fr];
  // w = logit + gumbel, overwrite acc0
#pragma unroll
  for (int i = 0; i < 4; ++i)
#pragma unroll
    for (int j = 0; j < 4; ++j) {
      const int col = bn + j * 16 + fr;
#pragma unroll
      for (int r = 0; r < 4; ++r) {
        const int row = bm + wm + i * 16 + q4 + r;
        const float logit = (acc0[i][j][r] + acc1[i][j][r] * s12) + bv[j];
        const unsigned gidx = ((unsigned)(step * B + row)) * (unsigned)V + (unsigned)col;
        acc0[i][j][r] = logit + gumbel_at(gidx);
      }
    }
  // per-row reduce over this block's 64 cols (within each 16-lane group)
  const int grp = bn >> 6;   // == blockIdx.y
#pragma unroll
  for (int i = 0; i < 4; ++i) {
#pragma unroll
    for (int r = 0; r < 4; ++r) {
      float mx = -INFINITY; int ix = 0;
#pragma unroll
      for (int j = 0; j < 4; ++j) {
        const float w = acc0[i][j][r];
        const int col = bn + j * 16 + fr;
        if (w > mx) { mx = w; ix = col; }
      }
#pragma unroll
      for (int m = 1; m < 16; m <<= 1) {
        const float om = __shfl_xor(mx, m, 64);
        const int oi = __shfl_xor(ix, m, 64);
        if (om > mx || (om == mx && oi < ix)) { mx = om; ix = oi; }
      }
      float s = 0.0f;
#pragma unroll
      for (int j = 0; j < 4; ++j) s += expf((acc0[i][j][r] - mx) / 1.2f);
#pragma unroll
      for (int m = 1; m < 16; m <<= 1) s += __shfl_xor(s, m, 64);
      if (fr == 0) {
        const int row = bm + wm + i * 16 + q4 + r;
        partM[(size_t)row * 64 + grp] = mx;
        partS[(size_t)row * 64 + grp] = s;
        partI[(size_t)row * 64 + grp] = ix;
      }
    }
  }
}

// ---------------- finalize: reduce partials, write, next emb ---------------
__global__ __launch_bounds__(256) void finalize_kernel(
    const float* __restrict__ partM, const float* __restrict__ partS,
    const int* __restrict__ partI,
    const float* __restrict__ emb,
    float* __restrict__ out,
    f16* __restrict__ e0, f16* __restrict__ e1,
    int step, int Tp1, int V, int E)
{
  const int b = blockIdx.x;
  const int tid = threadIdx.x;
  __shared__ float s_sc;
  __shared__ int s_tok;

  if (tid < 64) {
    const float m0 = partM[(size_t)b * 64 + tid];
    const float s0 = partS[(size_t)b * 64 + tid];
    const int i0 = partI[(size_t)b * 64 + tid];
    float mx = m0; int ix = i0;
#pragma unroll
    for (int m = 1; m < 64; m <<= 1) {
      const float om = __shfl_xor(mx, m, 64);
      const int oi = __shfl_xor(ix, m, 64);
      if (om > mx || (om == mx && oi < ix)) { mx = om; ix = oi; }
    }
    float c = s0 * expf((m0 - mx) / 1.2f);
#pragma unroll
    for (int m = 1; m < 64; m <<= 1) c += __shfl_xor(c, m, 64);
    if (tid == 0) {
      const float y = 1.0f / c;
      s_sc = (1.0f - y) + y;
      s_tok = ix;
    }
  }
  __syncthreads();
  const float sc = s_sc;
  const int tok = s_tok;

  // one-hot write: each thread builds its float4 in-register (no race)
  float* orow = out + ((size_t)b * Tp1 + step + 1) * V;
  const int tq = tok >> 2;
#pragma unroll
  for (int j = 0; j < 4; ++j) {
    const int idx = tid + 256 * j;
    float4 v = make_float4(0.f, 0.f, 0.f, 0.f);
    if (idx == tq) ((float*)&v)[tok & 3] = sc;
    ((float4*)orow)[idx] = v;
  }

  if (tid < E) {
    const float ev = sc * emb[(size_t)tok * E + tid];
    f16 h, l; split_f16(ev, h, l);
    e0[(size_t)b * E + tid] = h;
    e1[(size_t)b * E + tid] = l;
  }
}

// ------------------------------- host side ---------------------------------

extern "C" void kernel_launch(void* const* d_in, const int* in_sizes, int n_in,
                              void* d_out, int out_size, void* d_ws, size_t ws_size,
                              hipStream_t stream) {
  const float* t     = (const float*)d_in[0];
  const float* emb   = (const float*)d_in[1];
  const float* affw  = (const float*)d_in[2];
  const float* affb  = (const float*)d_in[3];
  const float* wih   = (const float*)d_in[4];
  const float* whh   = (const float*)d_in[5];
  const float* bih   = (const float*)d_in[6];
  const float* bhh   = (const float*)d_in[7];
  const float* lpw   = (const float*)d_in[8];
  const float* lpb   = (const float*)d_in[9];
  const int*   start = (const int*)d_in[10];
  float* out = (float*)d_out;

  const int H = in_sizes[3];             // 1024
  const int V = in_sizes[9];             // 4096
  const int E = in_sizes[1] / V;         // 256
  const int F = in_sizes[2] / H;         // 2048
  const int B = in_sizes[0] / F;         // 1024
  const int Tp1 = out_size / (B * V);    // 33
  const int T = Tp1 - 1;                 // 32
  const int KG = E + H;                  // 1280

  // ---- workspace layout (~65 MB) ----
  char* p = (char*)d_ws;
  float* cbuf  = (float*)p; p += (size_t)B * H * 4;           // 4 MB
  f16* hA0[2]; f16* hA1[2];
  hA0[0] = (f16*)p; p += (size_t)B * H * 2;
  hA1[0] = (f16*)p; p += (size_t)B * H * 2;
  hA0[1] = (f16*)p; p += (size_t)B * H * 2;
  hA1[1] = (f16*)p; p += (size_t)B * H * 2;                   // 8 MB
  f16* embA0 = (f16*)p; p += (size_t)B * E * 2;
  f16* embA1 = (f16*)p; p += (size_t)B * E * 2;               // 1 MB
  f16* wg0 = (f16*)p; p += (size_t)V * KG * 2;                // 20 MB packed gates
  f16* wg1 = (f16*)p; p += (size_t)V * KG * 2;
  f16* wl0 = (f16*)p; p += (size_t)V * H * 2;                 // 16 MB lp_w
  f16* wl1 = (f16*)p; p += (size_t)V * H * 2;
  f16* t0  = (f16*)p; p += (size_t)B * F * 2;                 // 8 MB t planes
  f16* t1  = (f16*)p; p += (size_t)B * F * 2;
  f16* aw0 = (f16*)p; p += (size_t)H * F * 2;                 // 8 MB aff_w planes
  f16* aw1 = (f16*)p; p += (size_t)H * F * 2;
  float* bgi = (float*)p; p += (size_t)V * 4;
  float* bgh = (float*)p; p += (size_t)V * 4;
  float* partM = (float*)p; p += (size_t)B * 64 * 4;
  float* partS = (float*)p; p += (size_t)B * 64 * 4;
  int*   partI = (int*)p;   p += (size_t)B * 64 * 4;
  (void)ws_size; (void)n_in;

  // ---- setup ----
  init_kernel<<<B, 256, 0, stream>>>(out, emb, embA0, embA1, start, Tp1, V, E);
  pack_gates_kernel<<<dim3((KG + 255) / 256, V), 256, 0, stream>>>(
      wih, whh, wg0, wg1, E, H, KG);
  pack_bias_kernel<<<V / 256, 256, 0, stream>>>(bih, bhh, bgi, bgh, H);
  split_kernel<<<(V * H + 255) / 256, 256, 0, stream>>>(lpw, wl0, wl1, V * H);
  split_kernel<<<(B * F + 255) / 256, 256, 0, stream>>>(t, t0, t1, B * F);
  split_kernel<<<(H * F + 255) / 256, 256, 0, stream>>>(affw, aw0, aw1, H * F);
  // h0 = t @ aff_w^T + aff_b -> split into hA[0]; zero cbuf
  // grid: x = row-block (fast, XCD-pinning), y = col strip
  h0_kernel<<<dim3(B / 128, H / 64), 128, 0, stream>>>(
      t0, t1, F, aw0, aw1, affb, hA0[0], hA1[0], H, cbuf);

  for (int s = 0; s < T; ++s) {
    const int cur = s & 1, nxt = (s + 1) & 1;
    gates_kernel<<<dim3(B / 128, V / 64), 128, 0, stream>>>(
        embA0, embA1, E, hA0[cur], hA1[cur], H,
        wg0, wg1, KG, bgi, bgh, cbuf, hA0[nxt], hA1[nxt]);
    logits_kernel<<<dim3(B / 128, V / 64), 128, 0, stream>>>(
        hA0[nxt], hA1[nxt], H, wl0, wl1, lpb,
        partM, partS, partI, s, B, V);
    finalize_kernel<<<B, 256, 0, stream>>>(
        partM, partS, partI, emb, out, embA0, embA1, s, Tp1, V, E);
  }
}

// Round 8
// 4757.920 us; speedup vs baseline: 1.1219x; 1.1219x over previous
//
#include <hip/hip_runtime.h>
#include <math.h>

// ---------------------------------------------------------------------------
// Sender: LSTM + Gumbel straight-through decode, 32 steps.
// Round 8: restore wave-level latency hiding. Same 128(M)x64(N) tile, BK=32,
// 512 blocks (r6 grid orientation), but 256 thr / 4 waves per block, each
// wave computing 32x64 -> 2 blocks/CU x 4 waves = 2 waves/SIMD from two
// DIFFERENT blocks (independent barriers) — the m97 overlap mechanism.
// VGPR/wave ~160 (acc 64 + frags 48), capped by __launch_bounds__(256,2).
// f16 2-way split (3 MFMA/product, exact products). Fused epilogues.
// ---------------------------------------------------------------------------

typedef _Float16 f16;
typedef f16 f16x8 __attribute__((ext_vector_type(8)));
typedef float f32x4 __attribute__((ext_vector_type(4)));

#define F16_MIN_NORM 6.104e-5f

__device__ __forceinline__ void split_f16(float v, f16& h, f16& l) {
  f16 h0 = (fabsf(v) < F16_MIN_NORM) ? (f16)0.0f : (f16)v;
  float r = (v - (float)h0) * 4096.0f;
  h = h0; l = (f16)r;
}

__device__ __forceinline__ float sigm(float x) { return 1.0f / (1.0f + expf(-x)); }

#define GLOAD_LDS16(gsrc, ldst)                                               \
  __builtin_amdgcn_global_load_lds(                                           \
      (const __attribute__((address_space(1))) unsigned int*)(const void*)(gsrc), \
      (__attribute__((address_space(3))) unsigned int*)(void*)(ldst), 16, 0, 0)

// --------------------------- threefry / gumbel -----------------------------

__device__ __forceinline__ unsigned tf_rotl(unsigned x, int r) {
  return (x << r) | (x >> (32 - r));
}

// JAX threefry2x32-20, key (0,42), partitionable: draw = x0_out ^ x1_out.
__device__ inline float gumbel_at(unsigned idx) {
  const unsigned ks0 = 0u;
  const unsigned ks1 = 42u;
  const unsigned ks2 = 0x1BD11BDAu ^ ks0 ^ ks1;
  unsigned x0 = 0u + ks0;
  unsigned x1 = idx + ks1;
#define TFR(rot) { x0 += x1; x1 = tf_rotl(x1, rot); x1 ^= x0; }
  TFR(13) TFR(15) TFR(26) TFR(6)
  x0 += ks1; x1 += ks2 + 1u;
  TFR(17) TFR(29) TFR(16) TFR(24)
  x0 += ks2; x1 += ks0 + 2u;
  TFR(13) TFR(15) TFR(26) TFR(6)
  x0 += ks0; x1 += ks1 + 3u;
  TFR(17) TFR(29) TFR(16) TFR(24)
  x0 += ks1; x1 += ks2 + 4u;
  TFR(13) TFR(15) TFR(26) TFR(6)
  x0 += ks2; x1 += ks0 + 5u;
#undef TFR
  const unsigned bits = x0 ^ x1;
  const float f = __uint_as_float((bits >> 9) | 0x3F800000u) - 1.0f;
  const float tiny = 1.17549435082228751e-38f;
  const float u = fmaxf(tiny, f * (1.0f - tiny) + tiny);
  return -logf(-logf(u));
}

// ------------------------- setup / pack kernels ----------------------------

__global__ void init_kernel(float* __restrict__ out, const float* __restrict__ emb,
                            f16* __restrict__ e0, f16* __restrict__ e1,
                            const int* __restrict__ startp, int Tp1, int V, int E) {
  const int b = blockIdx.x;
  const int start = *startp;
  float* orow = out + (size_t)b * Tp1 * V;
  const int tq = start >> 2;
  for (int v4 = threadIdx.x; v4 < V / 4; v4 += blockDim.x) {
    float4 v = make_float4(0.f, 0.f, 0.f, 0.f);
    if (v4 == tq) ((float*)&v)[start & 3] = 1.0f;
    ((float4*)orow)[v4] = v;
  }
  if (threadIdx.x < E) {
    const float v = emb[(size_t)start * E + threadIdx.x];
    f16 h, l; split_f16(v, h, l);
    e0[(size_t)b * E + threadIdx.x] = h;
    e1[(size_t)b * E + threadIdx.x] = l;
  }
}

// packed gate col p: gate q=(p>>4)&3, unit u=((p>>6)<<4)+(p&15); orig row
// n' = q*H + u. wpk[p][k] = k<E ? wih[n'][k] : whh[n'][k-E], split.
__global__ void pack_gates_kernel(const float* __restrict__ wih,
                                  const float* __restrict__ whh,
                                  f16* __restrict__ w0, f16* __restrict__ w1,
                                  int E, int H, int K) {
  const int k = blockIdx.x * blockDim.x + threadIdx.x;
  const int p = blockIdx.y;
  if (k >= K) return;
  const int n = ((p >> 4) & 3) * H + ((p >> 6) << 4) + (p & 15);
  const float v = (k < E) ? wih[(size_t)n * E + k] : whh[(size_t)n * H + (k - E)];
  f16 h, l; split_f16(v, h, l);
  w0[(size_t)p * K + k] = h;
  w1[(size_t)p * K + k] = l;
}

__global__ void pack_bias_kernel(const float* __restrict__ bih,
                                 const float* __restrict__ bhh,
                                 float* __restrict__ bi, float* __restrict__ bh, int H) {
  const int p = blockIdx.x * blockDim.x + threadIdx.x;
  const int n = ((p >> 4) & 3) * H + ((p >> 6) << 4) + (p & 15);
  bi[p] = bih[n];
  bh[p] = bhh[n];
}

__global__ void split_kernel(const float* __restrict__ in,
                             f16* __restrict__ o0, f16* __restrict__ o1, int n) {
  const int i = blockIdx.x * blockDim.x + threadIdx.x;
  if (i < n) { f16 h, l; split_f16(in[i], h, l); o0[i] = h; o1[i] = l; }
}

// ----------------------- shared K-loop building block ----------------------
// block 256 thr / 4 waves, tile 128x64, BK=32. Staging split into 24 1KB
// chunks (A-hi 8, A-lo 8, B-hi 4, B-lo 4), 6 per wave. Wave w computes
// rows [w*32, w*32+32) x all 64 cols.

__device__ __forceinline__ void stage_chunk(
    int chunk, int srow, int scol,
    const f16* __restrict__ a0s, const f16* __restrict__ a1s, int lda, int ka, int bm,
    const f16* __restrict__ b0s, const f16* __restrict__ b1s, int ldb, int kb, int bn,
    f16 (*ldsA0)[32], f16 (*ldsA1)[32], f16 (*ldsB0)[32], f16 (*ldsB1)[32])
{
  if (chunk < 8) {
    GLOAD_LDS16(a0s + (size_t)(bm + chunk * 16 + srow) * lda + ka + scol,
                &ldsA0[chunk * 16][0]);
  } else if (chunk < 16) {
    const int s = chunk - 8;
    GLOAD_LDS16(a1s + (size_t)(bm + s * 16 + srow) * lda + ka + scol,
                &ldsA1[s * 16][0]);
  } else if (chunk < 20) {
    const int s = chunk - 16;
    GLOAD_LDS16(b0s + (size_t)(bn + s * 16 + srow) * ldb + kb + scol,
                &ldsB0[s * 16][0]);
  } else {
    const int s = chunk - 20;
    GLOAD_LDS16(b1s + (size_t)(bn + s * 16 + srow) * ldb + kb + scol,
                &ldsB1[s * 16][0]);
  }
}

#define MFMA_DECLS                                                            \
  const int tid  = threadIdx.x;                                               \
  const int lane = tid & 63;                                                  \
  const int wid  = tid >> 6;                                                  \
  const int bm   = blockIdx.y * 128;                                          \
  const int bn   = blockIdx.x * 64;                                           \
  const int wm   = wid * 32;                                                  \
  const int fr   = lane & 15;                                                 \
  const int fk   = (lane >> 4) * 8;                                           \
  const int srow = lane >> 2;                                                 \
  const int scol = (lane & 3) * 8;                                            \
  f32x4 acc0[2][4], acc1[2][4];                                               \
  _Pragma("unroll") for (int i = 0; i < 2; ++i)                               \
  _Pragma("unroll") for (int j = 0; j < 4; ++j) {                             \
    acc0[i][j] = (f32x4)0.0f; acc1[i][j] = (f32x4)0.0f; }

#define MFMA_STAGE(a0s, a1s, lda, ka, b0s, b1s, ldb, kb)                      \
  __syncthreads();                                                            \
  _Pragma("unroll") for (int c = 0; c < 6; ++c)                               \
    stage_chunk(wid * 6 + c, srow, scol, (a0s), (a1s), (lda), (ka), bm,       \
                (b0s), (b1s), (ldb), (kb), bn, ldsA0, ldsA1, ldsB0, ldsB1);   \
  __syncthreads();

#define MFMA_COMPUTE                                                          \
  {                                                                           \
    f16x8 a0[2], a1[2], b0[4], b1[4];                                         \
    _Pragma("unroll") for (int i = 0; i < 2; ++i) {                           \
      a0[i] = *(const f16x8*)&ldsA0[wm + i * 16 + fr][fk];                    \
      a1[i] = *(const f16x8*)&ldsA1[wm + i * 16 + fr][fk];                    \
    }                                                                         \
    _Pragma("unroll") for (int j = 0; j < 4; ++j) {                           \
      b0[j] = *(const f16x8*)&ldsB0[j * 16 + fr][fk];                         \
      b1[j] = *(const f16x8*)&ldsB1[j * 16 + fr][fk];                         \
    }                                                                         \
    _Pragma("unroll") for (int i = 0; i < 2; ++i)                             \
    _Pragma("unroll") for (int j = 0; j < 4; ++j) {                           \
      acc0[i][j] = __builtin_amdgcn_mfma_f32_16x16x32_f16(a0[i], b0[j], acc0[i][j], 0, 0, 0); \
      acc1[i][j] = __builtin_amdgcn_mfma_f32_16x16x32_f16(a0[i], b1[j], acc1[i][j], 0, 0, 0); \
      acc1[i][j] = __builtin_amdgcn_mfma_f32_16x16x32_f16(a1[i], b0[j], acc1[i][j], 0, 0, 0); \
    }                                                                         \
  }

// ------------------- h0 GEMM: h0 = t @ aff_w^T + aff_b ---------------------
__global__ __launch_bounds__(256, 2) void h0_kernel(
    const f16* __restrict__ t0, const f16* __restrict__ t1, int F,
    const f16* __restrict__ aw0, const f16* __restrict__ aw1,
    const float* __restrict__ affb,
    f16* __restrict__ h0p, f16* __restrict__ h1p, int H,
    float* __restrict__ czero)
{
  __shared__ f16 ldsA0[128][32], ldsA1[128][32], ldsB0[64][32], ldsB1[64][32];
  MFMA_DECLS
  for (int kk = 0; kk < F; kk += 32) {
    MFMA_STAGE(t0, t1, F, kk, aw0, aw1, F, kk)
    MFMA_COMPUTE
  }
  const int q4 = (lane >> 4) * 4;
  const float s12 = 1.0f / 4096.0f;
#pragma unroll
  for (int j = 0; j < 4; ++j) {
    const int col = bn + j * 16 + fr;
    const float bb = affb[col];
#pragma unroll
    for (int i = 0; i < 2; ++i) {
#pragma unroll
      for (int r = 0; r < 4; ++r) {
        const int row = bm + wm + i * 16 + q4 + r;
        const float v = (acc0[i][j][r] + acc1[i][j][r] * s12) + bb;
        f16 hh, hl; split_f16(v, hh, hl);
        const size_t off = (size_t)row * H + col;
        h0p[off] = hh; h1p[off] = hl;
        czero[off] = 0.0f;
      }
    }
  }
}

// ---------------- gates GEMM + fused LSTM cell epilogue --------------------
__global__ __launch_bounds__(256, 2) void gates_kernel(
    const f16* __restrict__ e0, const f16* __restrict__ e1, int E,
    const f16* __restrict__ hin0, const f16* __restrict__ hin1, int H,
    const f16* __restrict__ w0, const f16* __restrict__ w1, int K,
    const float* __restrict__ bi, const float* __restrict__ bh,
    float* __restrict__ cbuf,
    f16* __restrict__ hout0, f16* __restrict__ hout1)
{
  __shared__ f16 ldsA0[128][32], ldsA1[128][32], ldsB0[64][32], ldsB1[64][32];
  MFMA_DECLS
  for (int kk = 0; kk < K; kk += 32) {
    const f16* a0s; const f16* a1s; int lda, ka;
    if (kk < E) { a0s = e0;   a1s = e1;   lda = E; ka = kk; }
    else        { a0s = hin0; a1s = hin1; lda = H; ka = kk - E; }
    MFMA_STAGE(a0s, a1s, lda, ka, w0, w1, K, kk)
    MFMA_COMPUTE
  }
  // epilogue: packed cols -> unit u = (bn>>2)+fr, gate q = j.
  const int q4 = (lane >> 4) * 4;
  const float s12 = 1.0f / 4096.0f;
  float biv[4], bhv[4];
#pragma unroll
  for (int j = 0; j < 4; ++j) {
    const int col = bn + j * 16 + fr;
    biv[j] = bi[col]; bhv[j] = bh[col];
  }
  const int nunit = (bn >> 2) + fr;
#pragma unroll
  for (int i = 0; i < 2; ++i) {
#pragma unroll
    for (int r = 0; r < 4; ++r) {
      const int row = bm + wm + i * 16 + q4 + r;
      float gv[4];
#pragma unroll
      for (int j = 0; j < 4; ++j)
        gv[j] = ((acc0[i][j][r] + acc1[i][j][r] * s12) + biv[j]) + bhv[j];
      const size_t off = (size_t)row * H + nunit;
      const float c = cbuf[off];
      const float cn = __fadd_rn(__fmul_rn(sigm(gv[1]), c),
                                 __fmul_rn(sigm(gv[0]), tanhf(gv[2])));
      const float hn = __fmul_rn(sigm(gv[3]), tanhf(cn));
      cbuf[off] = cn;
      f16 hh, hl; split_f16(hn, hh, hl);
      hout0[off] = hh; hout1[off] = hl;
    }
  }
}

// ------------- logits GEMM + fused sampling partials epilogue --------------
__global__ __launch_bounds__(256, 2) void logits_kernel(
    const f16* __restrict__ h0p, const f16* __restrict__ h1p, int H,
    const f16* __restrict__ w0, const f16* __restrict__ w1,
    const float* __restrict__ lpb,
    float* __restrict__ partM, float* __restrict__ partS, int* __restrict__ partI,
    int step, int B, int V)
{
  __shared__ f16 ldsA0[128][32], ldsA1[128][32], ldsB0[64][32], ldsB1[64][32];
  MFMA_DECLS
  for (int kk = 0; kk < H; kk += 32) {
    MFMA_STAGE(h0p, h1p, H, kk, w0, w1, H, kk)
    MFMA_COMPUTE
  }
  const int q4 = (lane >> 4) * 4;
  const float s12 = 1.0f / 4096.0f;
  float bv[4];
#pragma unroll
  for (int j = 0; j < 4; ++j) bv[j] = lpb[bn + j * 16 + fr];
  // w = logit + gumbel, overwrite acc0
#pragma unroll
  for (int i = 0; i < 2; ++i)
#pragma unroll
    for (int j = 0; j < 4; ++j) {
      const int col = bn + j * 16 + fr;
#pragma unroll
      for (int r = 0; r < 4; ++r) {
        const int row = bm + wm + i * 16 + q4 + r;
        const float logit = (acc0[i][j][r] + acc1[i][j][r] * s12) + bv[j];
        const unsigned gidx = ((unsigned)(step * B + row)) * (unsigned)V + (unsigned)col;
        acc0[i][j][r] = logit + gumbel_at(gidx);
      }
    }
  // per-row reduce over this block's 64 cols (within each 16-lane group)
  const int grp = bn >> 6;   // == blockIdx.x
#pragma unroll
  for (int i = 0; i < 2; ++i) {
#pragma unroll
    for (int r = 0; r < 4; ++r) {
      float mx = -INFINITY; int ix = 0;
#pragma unroll
      for (int j = 0; j < 4; ++j) {
        const float w = acc0[i][j][r];
        const int col = bn + j * 16 + fr;
        if (w > mx) { mx = w; ix = col; }
      }
#pragma unroll
      for (int m = 1; m < 16; m <<= 1) {
        const float om = __shfl_xor(mx, m, 64);
        const int oi = __shfl_xor(ix, m, 64);
        if (om > mx || (om == mx && oi < ix)) { mx = om; ix = oi; }
      }
      float s = 0.0f;
#pragma unroll
      for (int j = 0; j < 4; ++j) s += expf((acc0[i][j][r] - mx) / 1.2f);
#pragma unroll
      for (int m = 1; m < 16; m <<= 1) s += __shfl_xor(s, m, 64);
      if (fr == 0) {
        const int row = bm + wm + i * 16 + q4 + r;
        partM[(size_t)row * 64 + grp] = mx;
        partS[(size_t)row * 64 + grp] = s;
        partI[(size_t)row * 64 + grp] = ix;
      }
    }
  }
}

// ---------------- finalize: reduce partials, write, next emb ---------------
__global__ __launch_bounds__(256) void finalize_kernel(
    const float* __restrict__ partM, const float* __restrict__ partS,
    const int* __restrict__ partI,
    const float* __restrict__ emb,
    float* __restrict__ out,
    f16* __restrict__ e0, f16* __restrict__ e1,
    int step, int Tp1, int V, int E)
{
  const int b = blockIdx.x;
  const int tid = threadIdx.x;
  __shared__ float s_sc;
  __shared__ int s_tok;

  if (tid < 64) {
    const float m0 = partM[(size_t)b * 64 + tid];
    const float s0 = partS[(size_t)b * 64 + tid];
    const int i0 = partI[(size_t)b * 64 + tid];
    float mx = m0; int ix = i0;
#pragma unroll
    for (int m = 1; m < 64; m <<= 1) {
      const float om = __shfl_xor(mx, m, 64);
      const int oi = __shfl_xor(ix, m, 64);
      if (om > mx || (om == mx && oi < ix)) { mx = om; ix = oi; }
    }
    float c = s0 * expf((m0 - mx) / 1.2f);
#pragma unroll
    for (int m = 1; m < 64; m <<= 1) c += __shfl_xor(c, m, 64);
    if (tid == 0) {
      const float y = 1.0f / c;
      s_sc = (1.0f - y) + y;
      s_tok = ix;
    }
  }
  __syncthreads();
  const float sc = s_sc;
  const int tok = s_tok;

  // one-hot write: each thread builds its float4 in-register (no race)
  float* orow = out + ((size_t)b * Tp1 + step + 1) * V;
  const int tq = tok >> 2;
#pragma unroll
  for (int j = 0; j < 4; ++j) {
    const int idx = tid + 256 * j;
    float4 v = make_float4(0.f, 0.f, 0.f, 0.f);
    if (idx == tq) ((float*)&v)[tok & 3] = sc;
    ((float4*)orow)[idx] = v;
  }

  if (tid < E) {
    const float ev = sc * emb[(size_t)tok * E + tid];
    f16 h, l; split_f16(ev, h, l);
    e0[(size_t)b * E + tid] = h;
    e1[(size_t)b * E + tid] = l;
  }
}

// ------------------------------- host side ---------------------------------

extern "C" void kernel_launch(void* const* d_in, const int* in_sizes, int n_in,
                              void* d_out, int out_size, void* d_ws, size_t ws_size,
                              hipStream_t stream) {
  const float* t     = (const float*)d_in[0];
  const float* emb   = (const float*)d_in[1];
  const float* affw  = (const float*)d_in[2];
  const float* affb  = (const float*)d_in[3];
  const float* wih   = (const float*)d_in[4];
  const float* whh   = (const float*)d_in[5];
  const float* bih   = (const float*)d_in[6];
  const float* bhh   = (const float*)d_in[7];
  const float* lpw   = (const float*)d_in[8];
  const float* lpb   = (const float*)d_in[9];
  const int*   start = (const int*)d_in[10];
  float* out = (float*)d_out;

  const int H = in_sizes[3];             // 1024
  const int V = in_sizes[9];             // 4096
  const int E = in_sizes[1] / V;         // 256
  const int F = in_sizes[2] / H;         // 2048
  const int B = in_sizes[0] / F;         // 1024
  const int Tp1 = out_size / (B * V);    // 33
  const int T = Tp1 - 1;                 // 32
  const int KG = E + H;                  // 1280

  // ---- workspace layout (~65 MB) ----
  char* p = (char*)d_ws;
  float* cbuf  = (float*)p; p += (size_t)B * H * 4;           // 4 MB
  f16* hA0[2]; f16* hA1[2];
  hA0[0] = (f16*)p; p += (size_t)B * H * 2;
  hA1[0] = (f16*)p; p += (size_t)B * H * 2;
  hA0[1] = (f16*)p; p += (size_t)B * H * 2;
  hA1[1] = (f16*)p; p += (size_t)B * H * 2;                   // 8 MB
  f16* embA0 = (f16*)p; p += (size_t)B * E * 2;
  f16* embA1 = (f16*)p; p += (size_t)B * E * 2;               // 1 MB
  f16* wg0 = (f16*)p; p += (size_t)V * KG * 2;                // 20 MB packed gates
  f16* wg1 = (f16*)p; p += (size_t)V * KG * 2;
  f16* wl0 = (f16*)p; p += (size_t)V * H * 2;                 // 16 MB lp_w
  f16* wl1 = (f16*)p; p += (size_t)V * H * 2;
  f16* t0  = (f16*)p; p += (size_t)B * F * 2;                 // 8 MB t planes
  f16* t1  = (f16*)p; p += (size_t)B * F * 2;
  f16* aw0 = (f16*)p; p += (size_t)H * F * 2;                 // 8 MB aff_w planes
  f16* aw1 = (f16*)p; p += (size_t)H * F * 2;
  float* bgi = (float*)p; p += (size_t)V * 4;
  float* bgh = (float*)p; p += (size_t)V * 4;
  float* partM = (float*)p; p += (size_t)B * 64 * 4;
  float* partS = (float*)p; p += (size_t)B * 64 * 4;
  int*   partI = (int*)p;   p += (size_t)B * 64 * 4;
  (void)ws_size; (void)n_in;

  // ---- setup ----
  init_kernel<<<B, 256, 0, stream>>>(out, emb, embA0, embA1, start, Tp1, V, E);
  pack_gates_kernel<<<dim3((KG + 255) / 256, V), 256, 0, stream>>>(
      wih, whh, wg0, wg1, E, H, KG);
  pack_bias_kernel<<<V / 256, 256, 0, stream>>>(bih, bhh, bgi, bgh, H);
  split_kernel<<<(V * H + 255) / 256, 256, 0, stream>>>(lpw, wl0, wl1, V * H);
  split_kernel<<<(B * F + 255) / 256, 256, 0, stream>>>(t, t0, t1, B * F);
  split_kernel<<<(H * F + 255) / 256, 256, 0, stream>>>(affw, aw0, aw1, H * F);
  // h0 = t @ aff_w^T + aff_b -> split into hA[0]; zero cbuf
  h0_kernel<<<dim3(H / 64, B / 128), 256, 0, stream>>>(
      t0, t1, F, aw0, aw1, affb, hA0[0], hA1[0], H, cbuf);

  for (int s = 0; s < T; ++s) {
    const int cur = s & 1, nxt = (s + 1) & 1;
    gates_kernel<<<dim3(V / 64, B / 128), 256, 0, stream>>>(
        embA0, embA1, E, hA0[cur], hA1[cur], H,
        wg0, wg1, KG, bgi, bgh, cbuf, hA0[nxt], hA1[nxt]);
    logits_kernel<<<dim3(V / 64, B / 128), 256, 0, stream>>>(
        hA0[nxt], hA1[nxt], H, wl0, wl1, lpb,
        partM, partS, partI, s, B, V);
    finalize_kernel<<<B, 256, 0, stream>>>(
        partM, partS, partI, emb, out, embA0, embA1, s, Tp1, V, E);
  }
}